// Round 1
// baseline (232.351 us; speedup 1.0000x reference)
//
#include <hip/hip_runtime.h>
#include <hip/hip_bf16.h>

// Gaussians: quaternions (N,4) f32 + scales (N,3) f32 -> covariance (N,3,3) f32.
// C = (R*diag(s)) (R*diag(s))^T, i.e. C[i][k] = sum_j R[i][j]*R[k][j]*s[j]^2.
// Memory-bound: 64 B/point traffic, ~41 us roofline at 6.3 TB/s.

__global__ __launch_bounds__(256) void gaussians_cov_kernel(
    const float4* __restrict__ quat,   // N x 4
    const float*  __restrict__ scales, // N x 3
    float*        __restrict__ out,    // N x 9
    int n)
{
    int i = blockIdx.x * blockDim.x + threadIdx.x;
    if (i >= n) return;

    float4 q = quat[i];                 // coalesced 16B/lane
    float r = q.x, x = q.y, y = q.z, z = q.w;

    float nrm = sqrtf(r*r + x*x + y*y + z*z);
    nrm = fmaxf(nrm, 1e-12f);
    float inv = 1.0f / nrm;
    r *= inv; x *= inv; y *= inv; z *= inv;

    const float* sp = scales + 3ll * i;
    float sx = sp[0], sy = sp[1], sz = sp[2];

    // Rotation matrix rows
    float R00 = 1.0f - 2.0f*(y*y + z*z);
    float R01 = 2.0f*(x*y - r*z);
    float R02 = 2.0f*(x*z + r*y);
    float R10 = 2.0f*(x*y + r*z);
    float R11 = 1.0f - 2.0f*(x*x + z*z);
    float R12 = 2.0f*(y*z - r*x);
    float R20 = 2.0f*(x*z - r*y);
    float R21 = 2.0f*(y*z + r*x);
    float R22 = 1.0f - 2.0f*(x*x + y*y);

    float sx2 = sx*sx, sy2 = sy*sy, sz2 = sz*sz;

    // Symmetric covariance: 6 unique entries
    float c00 = R00*R00*sx2 + R01*R01*sy2 + R02*R02*sz2;
    float c01 = R00*R10*sx2 + R01*R11*sy2 + R02*R12*sz2;
    float c02 = R00*R20*sx2 + R01*R21*sy2 + R02*R22*sz2;
    float c11 = R10*R10*sx2 + R11*R11*sy2 + R12*R12*sz2;
    float c12 = R10*R20*sx2 + R11*R21*sy2 + R12*R22*sz2;
    float c22 = R20*R20*sx2 + R21*R21*sy2 + R22*R22*sz2;

    float* op = out + 9ll * i;
    op[0] = c00; op[1] = c01; op[2] = c02;
    op[3] = c01; op[4] = c11; op[5] = c12;
    op[6] = c02; op[7] = c12; op[8] = c22;
}

extern "C" void kernel_launch(void* const* d_in, const int* in_sizes, int n_in,
                              void* d_out, int out_size, void* d_ws, size_t ws_size,
                              hipStream_t stream)
{
    const float4* quat   = (const float4*)d_in[0];
    const float*  scales = (const float*)d_in[1];
    float*        out    = (float*)d_out;
    int n = in_sizes[0] / 4;   // quaternions is N x 4

    int block = 256;
    int grid  = (n + block - 1) / block;
    gaussians_cov_kernel<<<grid, block, 0, stream>>>(quat, scales, out, n);
}

// Round 2
// 225.432 us; speedup vs baseline: 1.0307x; 1.0307x over previous
//
#include <hip/hip_runtime.h>
#include <hip/hip_bf16.h>

// Gaussians: quaternions (N,4) f32 + scales (N,3) f32 -> covariance (N,3,3) f32.
// C = (R*diag(s)) (R*diag(s))^T  (symmetric: 6 unique entries).
// Memory-bound: 256 MB total traffic, ~41 us roofline at 6.3 TB/s.
// Strategy: block of 256 handles 256 points; LDS-stage scales (float4 loads)
// and covariance (float4 stores) so ALL global traffic is 16 B/lane coalesced.

#define BLK 256

__device__ __forceinline__ void compute_cov(float4 q, float sx, float sy, float sz,
                                            float* c /*6: 00,01,02,11,12,22*/)
{
    float r = q.x, x = q.y, y = q.z, z = q.w;
    float nrm = sqrtf(r*r + x*x + y*y + z*z);
    nrm = fmaxf(nrm, 1e-12f);
    float inv = 1.0f / nrm;
    r *= inv; x *= inv; y *= inv; z *= inv;

    float R00 = 1.0f - 2.0f*(y*y + z*z);
    float R01 = 2.0f*(x*y - r*z);
    float R02 = 2.0f*(x*z + r*y);
    float R10 = 2.0f*(x*y + r*z);
    float R11 = 1.0f - 2.0f*(x*x + z*z);
    float R12 = 2.0f*(y*z - r*x);
    float R20 = 2.0f*(x*z - r*y);
    float R21 = 2.0f*(y*z + r*x);
    float R22 = 1.0f - 2.0f*(x*x + y*y);

    float sx2 = sx*sx, sy2 = sy*sy, sz2 = sz*sz;

    c[0] = R00*R00*sx2 + R01*R01*sy2 + R02*R02*sz2; // 00
    c[1] = R00*R10*sx2 + R01*R11*sy2 + R02*R12*sz2; // 01
    c[2] = R00*R20*sx2 + R01*R21*sy2 + R02*R22*sz2; // 02
    c[3] = R10*R10*sx2 + R11*R11*sy2 + R12*R12*sz2; // 11
    c[4] = R10*R20*sx2 + R11*R21*sy2 + R12*R22*sz2; // 12
    c[5] = R20*R20*sx2 + R21*R21*sy2 + R22*R22*sz2; // 22
}

__global__ __launch_bounds__(BLK) void gaussians_cov_kernel(
    const float4* __restrict__ quat,    // N x 4 viewed as float4
    const float*  __restrict__ scales,  // N x 3 floats
    float*        __restrict__ out,     // N x 9 floats
    int n)
{
    __shared__ float s_sc[BLK * 3];     // 3 KB
    __shared__ float s_cov[BLK * 9];    // 9 KB

    const int t = threadIdx.x;
    const long long base = (long long)blockIdx.x * BLK;

    if (base + BLK <= n) {
        // ---- fast path: full block, fully vectorized global traffic ----
        // stage scales: 768 floats = 192 float4, coalesced
        if (t < (BLK * 3) / 4) {
            ((float4*)s_sc)[t] =
                ((const float4*)scales)[(long long)blockIdx.x * ((BLK * 3) / 4) + t];
        }
        float4 q = quat[base + t];      // coalesced 16 B/lane
        __syncthreads();

        // stride-3 LDS read: 2-way bank aliasing only (free on wave64/32-bank)
        float sx = s_sc[3*t], sy = s_sc[3*t+1], sz = s_sc[3*t+2];

        float c[6];
        compute_cov(q, sx, sy, sz, c);

        // stride-9 LDS write: odd stride -> 2-way aliasing, free
        float* cp = s_cov + 9 * t;
        cp[0] = c[0]; cp[1] = c[1]; cp[2] = c[2];
        cp[3] = c[1]; cp[4] = c[3]; cp[5] = c[4];
        cp[6] = c[2]; cp[7] = c[4]; cp[8] = c[5];
        __syncthreads();

        // blast 2304 floats = 576 float4 contiguous, coalesced 16 B/lane
        const float4* src = (const float4*)s_cov;
        float4* dst = (float4*)(out + base * 9);
        #pragma unroll
        for (int k = 0; k < (BLK * 9) / 4; k += BLK) {
            int idx = k + t;
            if (idx < (BLK * 9) / 4) dst[idx] = src[idx];
        }
    } else {
        // ---- tail path (unused for N=4M but kept correct for any n) ----
        long long i = base + t;
        if (i < n) {
            float4 q = quat[i];
            const float* sp = scales + 3 * i;
            float c[6];
            compute_cov(q, sp[0], sp[1], sp[2], c);
            float* op = out + 9 * i;
            op[0] = c[0]; op[1] = c[1]; op[2] = c[2];
            op[3] = c[1]; op[4] = c[3]; op[5] = c[4];
            op[6] = c[2]; op[7] = c[4]; op[8] = c[5];
        }
    }
}

extern "C" void kernel_launch(void* const* d_in, const int* in_sizes, int n_in,
                              void* d_out, int out_size, void* d_ws, size_t ws_size,
                              hipStream_t stream)
{
    const float4* quat   = (const float4*)d_in[0];
    const float*  scales = (const float*)d_in[1];
    float*        out    = (float*)d_out;
    int n = in_sizes[0] / 4;   // quaternions is N x 4

    int grid = (n + BLK - 1) / BLK;
    gaussians_cov_kernel<<<grid, BLK, 0, stream>>>(quat, scales, out, n);
}

// Round 4
// 221.205 us; speedup vs baseline: 1.0504x; 1.0191x over previous
//
#include <hip/hip_runtime.h>
#include <hip/hip_bf16.h>

// Gaussians: quaternions (N,4) f32 + scales (N,3) f32 -> covariance (N,3,3) f32.
// C = (R*diag(s)) (R*diag(s))^T  (symmetric: 6 unique entries).
// Memory-bound: 256 MB total traffic, ~41 us pure-traffic floor at 6.3 TB/s.
// R3b: 2 points/thread (load ILP), scales direct (L1 absorbs the stride-3
// re-reads), LDS staging for stores only (single barrier), nt hints on the
// single-touch streams via native clang vector type (HIP_vector_type is
// rejected by __builtin_nontemporal_*).

#define BLK 256
#define PPT 2
#define PPB (BLK * PPT)   // 512 points per block

typedef float vfloat4 __attribute__((ext_vector_type(4)));

__device__ __forceinline__ void compute_cov(vfloat4 q, float sx, float sy, float sz,
                                            float* c /*6: 00,01,02,11,12,22*/)
{
    float r = q.x, x = q.y, y = q.z, z = q.w;
    float nrm = sqrtf(r*r + x*x + y*y + z*z);
    nrm = fmaxf(nrm, 1e-12f);
    float inv = 1.0f / nrm;
    r *= inv; x *= inv; y *= inv; z *= inv;

    float R00 = 1.0f - 2.0f*(y*y + z*z);
    float R01 = 2.0f*(x*y - r*z);
    float R02 = 2.0f*(x*z + r*y);
    float R10 = 2.0f*(x*y + r*z);
    float R11 = 1.0f - 2.0f*(x*x + z*z);
    float R12 = 2.0f*(y*z - r*x);
    float R20 = 2.0f*(x*z - r*y);
    float R21 = 2.0f*(y*z + r*x);
    float R22 = 1.0f - 2.0f*(x*x + y*y);

    float sx2 = sx*sx, sy2 = sy*sy, sz2 = sz*sz;

    c[0] = R00*R00*sx2 + R01*R01*sy2 + R02*R02*sz2; // 00
    c[1] = R00*R10*sx2 + R01*R11*sy2 + R02*R12*sz2; // 01
    c[2] = R00*R20*sx2 + R01*R21*sy2 + R02*R22*sz2; // 02
    c[3] = R10*R10*sx2 + R11*R11*sy2 + R12*R12*sz2; // 11
    c[4] = R10*R20*sx2 + R11*R21*sy2 + R12*R22*sz2; // 12
    c[5] = R20*R20*sx2 + R21*R21*sy2 + R22*R22*sz2; // 22
}

__global__ __launch_bounds__(BLK) void gaussians_cov_kernel(
    const vfloat4* __restrict__ quat,   // N x 4 viewed as float4
    const float*   __restrict__ scales, // N x 3 floats
    float*         __restrict__ out,    // N x 9 floats
    int n)
{
    __shared__ float s_cov[PPB * 9];    // 18 KB

    const int t = threadIdx.x;
    const long long base = (long long)blockIdx.x * PPB;

    if (base + PPB <= n) {
        // ---- fast path: two independent points per thread ----
        vfloat4 q0 = __builtin_nontemporal_load(&quat[base + t]);
        vfloat4 q1 = __builtin_nontemporal_load(&quat[base + BLK + t]);

        const float* sp0 = scales + 3 * (base + t);
        const float* sp1 = scales + 3 * (base + BLK + t);
        float s0x = sp0[0], s0y = sp0[1], s0z = sp0[2];
        float s1x = sp1[0], s1y = sp1[1], s1z = sp1[2];

        float c0[6], c1[6];
        compute_cov(q0, s0x, s0y, s0z, c0);
        compute_cov(q1, s1x, s1y, s1z, c1);

        // stride-9 LDS writes: odd stride -> 2-way bank aliasing, free
        float* cp0 = s_cov + 9 * t;
        cp0[0] = c0[0]; cp0[1] = c0[1]; cp0[2] = c0[2];
        cp0[3] = c0[1]; cp0[4] = c0[3]; cp0[5] = c0[4];
        cp0[6] = c0[2]; cp0[7] = c0[4]; cp0[8] = c0[5];
        float* cp1 = s_cov + 9 * (BLK + t);
        cp1[0] = c1[0]; cp1[1] = c1[1]; cp1[2] = c1[2];
        cp1[3] = c1[1]; cp1[4] = c1[3]; cp1[5] = c1[4];
        cp1[6] = c1[2]; cp1[7] = c1[4]; cp1[8] = c1[5];
        __syncthreads();

        // blast 4608 floats = 1152 float4 contiguous, nt coalesced stores
        const vfloat4* src = (const vfloat4*)s_cov;
        vfloat4* dst = (vfloat4*)(out + base * 9);
        #pragma unroll
        for (int k = 0; k < 5; ++k) {
            int idx = k * BLK + t;
            if (idx < (PPB * 9) / 4)
                __builtin_nontemporal_store(src[idx], &dst[idx]);
        }
    } else {
        // ---- tail path (last partial block) ----
        for (int p = 0; p < PPT; ++p) {
            long long i = base + p * BLK + t;
            if (i < n) {
                vfloat4 q = quat[i];
                const float* sp = scales + 3 * i;
                float c[6];
                compute_cov(q, sp[0], sp[1], sp[2], c);
                float* op = out + 9 * i;
                op[0] = c[0]; op[1] = c[1]; op[2] = c[2];
                op[3] = c[1]; op[4] = c[3]; op[5] = c[4];
                op[6] = c[2]; op[7] = c[4]; op[8] = c[5];
            }
        }
    }
}

extern "C" void kernel_launch(void* const* d_in, const int* in_sizes, int n_in,
                              void* d_out, int out_size, void* d_ws, size_t ws_size,
                              hipStream_t stream)
{
    const vfloat4* quat   = (const vfloat4*)d_in[0];
    const float*   scales = (const float*)d_in[1];
    float*         out    = (float*)d_out;
    int n = in_sizes[0] / 4;   // quaternions is N x 4

    int grid = (n + PPB - 1) / PPB;
    gaussians_cov_kernel<<<grid, BLK, 0, stream>>>(quat, scales, out, n);
}